// Round 6
// baseline (860.307 us; speedup 1.0000x reference)
//
#include <hip/hip_runtime.h>

// ---------------------------------------------------------------------------
// 2-layer LSTM (H=51) + Linear(51,1), B=1024, T=1024, fp32.
// R19 = R18 with 8 fat waves + k-permuted h layout.
//   Post-mortem R18: VALU cut matched counters but time flat -> pacer is the
//   per-CU DS pipe in the post-barrier lockstep burst: 52 b128 reads (624cy)
//   + 268cy/step measured bank conflicts (h-store q-pairs share a dword).
//   - 8 waves (512 thr, waves_per_eu(2,2)): waves 0-5 own tiles {w,7+w},
//     wave 6 tile 6, wave 7 y. B-frags shared across a wave's tiles ->
//     DS reads 52+2 -> 30 b128/step. Barrier population halves.
//   - h-plane k-PERMUTATION posu(u)=(u&~7)|((u&3)<<1)|((u>>2)&1): a wave's
//     4 consecutive u land in 4 distinct dwords -> 64-lane b16 store covers
//     32 banks exactly 2-way (free). Reads unchanged (contiguous). Exactness:
//     inverse perm applied to A-frag k-columns and y-weights (MFMA sums over
//     k -> any consistent relabeling is exact).
//   - Rest R17/R18-proven: fp16 single-term MFMA (6/tile-step), fused-rcp
//     cells (16 trans/cell-pair), exp2-domain gates, bias+Wx in acc init,
//     unroll x2 (rb/wbuf literal), plane stride 88 (176B) conflict-free b128,
//     ONE barrier/step, L2 one step behind L1, ping-pong buffers, deferred
//     y(k-2) on the y-wave, peeled k=0/1.
// ---------------------------------------------------------------------------

#define H     51
#define NROW  204      // 4*H
#define TLEN  1024
#define BPB   16       // batches per block (= mfma N)
#define NTHR  512      // 8 waves
#define NBLK  64
#define KPAD  88       // fp16 row stride (176B) -> conflict-free b128 reads

#define LOG2E  1.442695041f
#define LOG2E2 2.885390082f

typedef __attribute__((ext_vector_type(8))) _Float16 half8;  // 8 f16 = 4 VGPRs
typedef __attribute__((ext_vector_type(4))) float f4;

__device__ __forceinline__ float frcp(float x) { return __builtin_amdgcn_rcpf(x); }
#if __has_builtin(__builtin_amdgcn_exp2f)
__device__ __forceinline__ float ex2(float x) { return __builtin_amdgcn_exp2f(x); }
#else
__device__ __forceinline__ float ex2(float x) { return __expf(x * 0.6931471806f); }
#endif

// k-layout permutation within each 8-group: unit u stored at LDS position
// posu(u). Write spread: q=0..3 (consecutive u) -> 4 distinct dwords.
__device__ __forceinline__ int posu(int u) {
    return (u & ~7) | ((u & 3) << 1) | ((u >> 2) & 1);
}
__device__ __forceinline__ int ipos(int p) {   // inverse of posu
    return (p & ~7) | ((p & 1) << 2) | ((p >> 1) & 3);
}

__device__ __forceinline__ half8 lds8h(const _Float16* p) {  // one ds_read_b128
    return *(const half8*)__builtin_assume_aligned(p, 16);
}

#define MFMA(ACC, A, B) \
    ACC = __builtin_amdgcn_mfma_f32_16x16x32_f16((A), (B), (ACC), 0, 0, 0)

// A-frag for 16x16x32: lane holds A[m=lane&15][k=quad*8+j], j=0..7.
// Source W is [204][51] row-major, PyTorch rows g*51+u; permuted row
// prow = 4u+g -> src row = (prow&3)*51 + (prow>>2). Column for register j is
// the unit stored at LDS position kt*32+q*8+j, i.e. ipos(...). Zero-pad
// prow>=204 and unit>=51. Rows pre-scaled by log2e (2log2e for gate g).
__device__ __forceinline__ half8 load_wfrag(const float* __restrict__ W,
                                            int tile, int kt, int q, int mcol)
{
    half8 hf;
    const int prow = tile * 16 + mcol;
    const float sc = ((prow & 3) == 2) ? LOG2E2 : LOG2E;
#pragma unroll
    for (int j = 0; j < 8; ++j) {
        const int kk = ipos(kt * 32 + q * 8 + j);    // permuted k layout
        float v = 0.0f;
        if (prow < NROW && kk < H) {
            const int srow = (prow & 3) * H + (prow >> 2);
            v = W[srow * H + kk];
        }
        hf[j] = (_Float16)(v * sc);
    }
    return hf;
}

// Fused LSTM cell (exp2-domain pre-activations), 5 ex2 + 3 rcp:
//   c' = c*rcp(1+e_f) + (Eg-1)*rcp((1+e_i)(Eg+1))
//   h' = (Ec-1)*rcp((Ec+1)(1+e_o))
__device__ __forceinline__ float cell(float a_i, float a_f, float b_g,
                                      float d_o, float* c)
{
    const float e_i = ex2(-a_i);
    const float e_f = ex2(-a_f);
    const float Eg  = ex2(b_g);
    const float f   = frcp(1.0f + e_f);
    const float ig  = (Eg - 1.0f) * frcp((1.0f + e_i) * (Eg + 1.0f));
    const float cn  = fmaf(f, *c, ig);
    *c = cn;
    const float Ec  = ex2(cn * LOG2E2);
    const float e_o = ex2(-d_o);
    return (Ec - 1.0f) * frcp((Ec + 1.0f) * (1.0f + e_o));
}

__global__
__attribute__((amdgpu_flat_work_group_size(NTHR, NTHR), amdgpu_waves_per_eu(2, 2)))
void lstm2_kernel(const float* __restrict__ input,
                  const float* __restrict__ W_ih1, const float* __restrict__ W_hh1,
                  const float* __restrict__ b_ih1, const float* __restrict__ b_hh1,
                  const float* __restrict__ W_ih2, const float* __restrict__ W_hh2,
                  const float* __restrict__ b_ih2, const float* __restrict__ b_hh2,
                  const float* __restrict__ W_lin, const float* __restrict__ b_lin,
                  float* __restrict__ out)
{
    const int tid  = threadIdx.x;
    const int w    = tid >> 6;        // wave 0..7
    const int lane = tid & 63;
    const int q    = lane >> 4;       // quad
    const int mcol = lane & 15;       // batch column (and A-frag m)
    const int b0   = blockIdx.x * BPB;

    const bool tile_wave = (w < 7);
    const bool y_wave    = (w == 7);

    // [buf][plane][mcol][kpos]; planes: 0=h1 1=h2 (fp16, k-permuted layout).
    // Positions for units>=51 stay zero (init below; unit 51 writes exact 0).
    __shared__ __align__(16) _Float16 hb[2][2][BPB][KPAD];

    {
        _Float16* hz = &hb[0][0][0][0];
        for (int i = tid; i < 2 * 2 * BPB * KPAD; i += NTHR) hz[i] = (_Float16)0.0f;
    }

    // ---- persistent weight fragments: wave w owns tiles {w, 7+w} ----------
    const int t0 = w;
    const int t1 = 7 + w;
    const bool s2 = tile_wave && (t1 < 13);   // waves 0..5 have a 2nd tile

    half8 A1[2][2], Ai[2][2], Ah[2][2];       // [slot][ktile]
    f4 bb1[2], bb2[2], wxv[2];
    float c1_0 = 0.0f, c2_0 = 0.0f, c1_1 = 0.0f, c2_1 = 0.0f;
    int   wp0 = 0, wp1 = 0;                   // permuted write positions

    if (tile_wave) {
        const int tt[2] = {t0, t1};
#pragma unroll
        for (int s = 0; s < 2; ++s) {
            const int t = tt[s];
            const int u = 4 * t + q;
            if (s == 0) wp0 = posu(u); else wp1 = posu(u);
            if (t < 13) {
#pragma unroll
                for (int kt = 0; kt < 2; ++kt) {
                    A1[s][kt] = load_wfrag(W_hh1, t, kt, q, mcol);
                    Ai[s][kt] = load_wfrag(W_ih2, t, kt, q, mcol);
                    Ah[s][kt] = load_wfrag(W_hh2, t, kt, q, mcol);
                }
#pragma unroll
                for (int j = 0; j < 4; ++j) {  // gate j of unit u (row j*H+u)
                    const bool v = (u < H);
                    const float sc = (j == 2) ? LOG2E2 : LOG2E;
                    bb1[s][j] = v ? sc * (b_ih1[j * H + u] + b_hh1[j * H + u]) : 0.0f;
                    bb2[s][j] = v ? sc * (b_ih2[j * H + u] + b_hh2[j * H + u]) : 0.0f;
                    wxv[s][j] = v ? sc * W_ih1[j * H + u] : 0.0f;
                }
            }
        }
    }

    float wl[16];                     // y-wave: weights for PERMUTED positions
    if (y_wave) {
#pragma unroll
        for (int i = 0; i < 16; ++i) {
            const int r = ipos(q * 16 + i);
            wl[i] = (r < H) ? W_lin[r] : 0.0f;
        }
    }
    const float blin = b_lin[0];

    float xcur = input[(size_t)(b0 + mcol) * TLEN + 0];

    __syncthreads();                  // zeros visible

// One LSTM step: reads buf RB (h1(k-1), h2(k-2)), writes buf WB.
// RB/WB/L2EN/YEN literals -> guards fold, LDS addresses loop-invariant.
#define STEP(KK, RB, WB, L2EN, YEN)                                            \
do {                                                                           \
    const int k_  = (KK);                                                      \
    const int kn_ = (k_ + 1 < TLEN) ? (k_ + 1) : (TLEN - 1);                   \
    const float xnext_ = input[(size_t)(b0 + mcol) * TLEN + kn_];              \
    if (tile_wave) {                                                           \
        half8 B1a = lds8h(&hb[RB][0][mcol][q * 8]);                            \
        half8 B1b = lds8h(&hb[RB][0][mcol][32 + q * 8]);                       \
        f4 g1_0;                                                               \
        g1_0[0] = fmaf(wxv[0][0], xcur, bb1[0][0]);                            \
        g1_0[1] = fmaf(wxv[0][1], xcur, bb1[0][1]);                            \
        g1_0[2] = fmaf(wxv[0][2], xcur, bb1[0][2]);                            \
        g1_0[3] = fmaf(wxv[0][3], xcur, bb1[0][3]);                            \
        MFMA(g1_0, A1[0][0], B1a);  MFMA(g1_0, A1[0][1], B1b);                 \
        if (s2) {                                                              \
            f4 g1_1;                                                           \
            g1_1[0] = fmaf(wxv[1][0], xcur, bb1[1][0]);                        \
            g1_1[1] = fmaf(wxv[1][1], xcur, bb1[1][1]);                        \
            g1_1[2] = fmaf(wxv[1][2], xcur, bb1[1][2]);                        \
            g1_1[3] = fmaf(wxv[1][3], xcur, bb1[1][3]);                        \
            MFMA(g1_1, A1[1][0], B1a);  MFMA(g1_1, A1[1][1], B1b);             \
            const float h1n1 = cell(g1_1[0], g1_1[1], g1_1[2], g1_1[3], &c1_1);\
            hb[WB][0][mcol][wp1] = (_Float16)h1n1;                             \
        }                                                                      \
        const float h1n0 = cell(g1_0[0], g1_0[1], g1_0[2], g1_0[3], &c1_0);    \
        hb[WB][0][mcol][wp0] = (_Float16)h1n0;                                 \
        if (L2EN) {                                                            \
            half8 B2a = lds8h(&hb[RB][1][mcol][q * 8]);                        \
            half8 B2b = lds8h(&hb[RB][1][mcol][32 + q * 8]);                   \
            f4 g2_0 = bb2[0];                                                  \
            MFMA(g2_0, Ai[0][0], B1a);  MFMA(g2_0, Ai[0][1], B1b);             \
            MFMA(g2_0, Ah[0][0], B2a);  MFMA(g2_0, Ah[0][1], B2b);             \
            if (s2) {                                                          \
                f4 g2_1 = bb2[1];                                              \
                MFMA(g2_1, Ai[1][0], B1a);  MFMA(g2_1, Ai[1][1], B1b);         \
                MFMA(g2_1, Ah[1][0], B2a);  MFMA(g2_1, Ah[1][1], B2b);         \
                const float h2n1 = cell(g2_1[0], g2_1[1], g2_1[2], g2_1[3], &c2_1); \
                hb[WB][1][mcol][wp1] = (_Float16)h2n1;                         \
            }                                                                  \
            const float h2n0 = cell(g2_0[0], g2_0[1], g2_0[2], g2_0[3], &c2_0);\
            hb[WB][1][mcol][wp0] = (_Float16)h2n0;                             \
        }                                                                      \
    } else if (y_wave && (YEN)) {                                              \
        /* deferred y(k-2) from h2 plane of buf RB (stable this iter) */       \
        half8 y0 = lds8h(&hb[RB][1][mcol][q * 16]);                            \
        half8 y1 = lds8h(&hb[RB][1][mcol][q * 16 + 8]);                        \
        float yp = 0.0f;                                                       \
        _Pragma("unroll")                                                      \
        for (int i = 0; i < 8; ++i) {                                          \
            yp += wl[i]     * (float)y0[i];                                    \
            yp += wl[i + 8] * (float)y1[i];                                    \
        }                                                                      \
        yp += __shfl_xor(yp, 16);                                              \
        yp += __shfl_xor(yp, 32);                                              \
        if (q == 0) out[(size_t)(b0 + mcol) * TLEN + (k_ - 2)] = yp + blin;    \
    }                                                                          \
    __syncthreads();                                                           \
    xcur = xnext_;                                                             \
} while (0)

    // k even: rb=1, wbuf=0; k odd: rb=0, wbuf=1.
    STEP(0, 1, 0, 0, 0);                   // L1 only (h2(-1) stays 0)
    STEP(1, 0, 1, 1, 0);                   // +L2 (step 0); y starts at k=2
    for (int k = 2; k < TLEN; k += 2) {    // steady: no guards
        STEP(k, 1, 0, 1, 1);
        STEP(k + 1, 0, 1, 1, 1);
    }
    STEP(TLEN, 1, 0, 1, 1);                // tail: L2(step 1023) + y(1022)
#undef STEP

    // epilogue: y(T-1) from h2 plane of buf (TLEN & 1) = 0 (= wbuf at k=TLEN)
    if (y_wave) {
        half8 y0 = lds8h(&hb[0][1][mcol][q * 16]);
        half8 y1 = lds8h(&hb[0][1][mcol][q * 16 + 8]);
        float yp = 0.0f;
#pragma unroll
        for (int i = 0; i < 8; ++i) {
            yp += wl[i]     * (float)y0[i];
            yp += wl[i + 8] * (float)y1[i];
        }
        yp += __shfl_xor(yp, 16);
        yp += __shfl_xor(yp, 32);
        if (q == 0) out[(size_t)(b0 + mcol) * TLEN + (TLEN - 1)] = yp + blin;
    }
}

extern "C" void kernel_launch(void* const* d_in, const int* in_sizes, int n_in,
                              void* d_out, int out_size, void* d_ws, size_t ws_size,
                              hipStream_t stream)
{
    const float* input = (const float*)d_in[0];
    const float* W_ih1 = (const float*)d_in[1];
    const float* W_hh1 = (const float*)d_in[2];
    const float* b_ih1 = (const float*)d_in[3];
    const float* b_hh1 = (const float*)d_in[4];
    const float* W_ih2 = (const float*)d_in[5];
    const float* W_hh2 = (const float*)d_in[6];
    const float* b_ih2 = (const float*)d_in[7];
    const float* b_hh2 = (const float*)d_in[8];
    const float* W_lin = (const float*)d_in[9];
    const float* b_lin = (const float*)d_in[10];

    float* out = (float*)d_out;

    hipLaunchKernelGGL(lstm2_kernel, dim3(NBLK), dim3(NTHR), 0, stream,
                       input, W_ih1, W_hh1, b_ih1, b_hh1,
                       W_ih2, W_hh2, b_ih2, b_hh2, W_lin, b_lin,
                       out);
}

// Round 7
// 772.020 us; speedup vs baseline: 1.1144x; 1.1144x over previous
//
#include <hip/hip_runtime.h>

// ---------------------------------------------------------------------------
// 2-layer LSTM (H=51) + Linear(51,1), B=1024, T=1024, fp32.
// R20 = R18 (14-wave shape, best 715us) + posu store-spread + lgkm-only
//       raw barrier.
//   Post-mortem R19: 8 fat waves REGRESSED (807us) - 2 waves/SIMD doubled
//   the per-wave serial tail; 14 thin waves proven best (R16/R19 A/B).
//   Conflict arithmetic: R17/R18's h-store at element u puts q-pairs in the
//   same dword -> 64-lane ds_write_b16 hits 8 banks 4-way = ~300cy/step,
//   matching the 1.76e7 counter. Fix in the RIGHT shape this time:
//   - posu(u)=(u&~7)|((u&3)<<1)|((u>>2)&1): wave's 4 units -> 4 distinct
//     dwords -> stores cover 32 banks exactly 2-way (free). Reads unchanged
//     (contiguous b128). Exact: ipos applied to A-frag k-columns and
//     y-weights (k-relabeling under MFMA sum).
//   - raw "s_waitcnt lgkmcnt(0); s_barrier" per step (not __syncthreads):
//     drops the per-step vmcnt(0) drain that serialized the in-flight xnext
//     global load into the barrier. LDS ordering fully covered by lgkmcnt.
//     Uniform control flow (every wave executes STEP) -> barrier safe.
//   - Rest R17/R18-proven: fp16 single-term MFMA (6/tile-step), fused-rcp
//     cells (16 trans/cell-pair), exp2-domain gates, bias+Wx in acc init,
//     unroll x2 (rb/wbuf literal), 14 waves (13 tile + 1 y) waves_per_eu(4,4),
//     prow=4u+g lane-local acts, plane stride 88 (176B) conflict-free b128,
//     ONE barrier/step, L2 one step behind L1, ping-pong buffers, deferred
//     y(k-2) on wave 13, peeled k=0/1.
// ---------------------------------------------------------------------------

#define H     51
#define NROW  204      // 4*H
#define TLEN  1024
#define BPB   16       // batches per block (= mfma N)
#define NTHR  896      // 14 waves
#define NBLK  64
#define KPAD  88       // fp16 row stride (176B) -> conflict-free b128 reads

#define LOG2E  1.442695041f
#define LOG2E2 2.885390082f

typedef __attribute__((ext_vector_type(8))) _Float16 half8;  // 8 f16 = 4 VGPRs
typedef __attribute__((ext_vector_type(4))) float f4;

__device__ __forceinline__ float frcp(float x) { return __builtin_amdgcn_rcpf(x); }
#if __has_builtin(__builtin_amdgcn_exp2f)
__device__ __forceinline__ float ex2(float x) { return __builtin_amdgcn_exp2f(x); }
#else
__device__ __forceinline__ float ex2(float x) { return __expf(x * 0.6931471806f); }
#endif

// k-layout permutation within each 8-group: unit u stored at LDS position
// posu(u). A wave's 4 consecutive u (q=0..3) -> 4 distinct dwords.
__device__ __forceinline__ int posu(int u) {
    return (u & ~7) | ((u & 3) << 1) | ((u >> 2) & 1);
}
__device__ __forceinline__ int ipos(int p) {   // inverse of posu
    return (p & ~7) | ((p & 1) << 2) | ((p >> 1) & 3);
}

__device__ __forceinline__ half8 lds8h(const _Float16* p) {  // one ds_read_b128
    return *(const half8*)__builtin_assume_aligned(p, 16);
}

// LDS-only barrier: all prior DS ops complete, then s_barrier. No vmcnt
// drain (xnext global load stays in flight; compiler waits before its use).
__device__ __forceinline__ void block_sync_lds() {
    asm volatile("s_waitcnt lgkmcnt(0)\n\ts_barrier" ::: "memory");
}

#define MFMA(ACC, A, B) \
    ACC = __builtin_amdgcn_mfma_f32_16x16x32_f16((A), (B), (ACC), 0, 0, 0)

// A-frag for 16x16x32: lane holds A[m=lane&15][k=quad*8+j], j=0..7.
// Source W is [204][51] row-major, PyTorch rows g*51+u; permuted row
// prow = 4u+g -> src row = (prow&3)*51 + (prow>>2). Column for register j is
// the unit stored at LDS position kt*32+q*8+j, i.e. ipos(...). Zero-pad
// prow>=204 and unit>=51. Rows pre-scaled by log2e (2log2e for gate g).
__device__ __forceinline__ half8 load_wfrag(const float* __restrict__ W,
                                            int tile, int kt, int q, int mcol)
{
    half8 hf;
    const int prow = tile * 16 + mcol;
    const float sc = ((prow & 3) == 2) ? LOG2E2 : LOG2E;
#pragma unroll
    for (int j = 0; j < 8; ++j) {
        const int kk = ipos(kt * 32 + q * 8 + j);    // permuted k layout
        float v = 0.0f;
        if (prow < NROW && kk < H) {
            const int srow = (prow & 3) * H + (prow >> 2);
            v = W[srow * H + kk];
        }
        hf[j] = (_Float16)(v * sc);
    }
    return hf;
}

// Fused LSTM cell (exp2-domain pre-activations), 5 ex2 + 3 rcp:
//   c' = c*rcp(1+e_f) + (Eg-1)*rcp((1+e_i)(Eg+1))
//   h' = (Ec-1)*rcp((Ec+1)(1+e_o))
__device__ __forceinline__ float cell(float a_i, float a_f, float b_g,
                                      float d_o, float* c)
{
    const float e_i = ex2(-a_i);
    const float e_f = ex2(-a_f);
    const float Eg  = ex2(b_g);
    const float f   = frcp(1.0f + e_f);
    const float ig  = (Eg - 1.0f) * frcp((1.0f + e_i) * (Eg + 1.0f));
    const float cn  = fmaf(f, *c, ig);
    *c = cn;
    const float Ec  = ex2(cn * LOG2E2);
    const float e_o = ex2(-d_o);
    return (Ec - 1.0f) * frcp((Ec + 1.0f) * (1.0f + e_o));
}

__global__
__attribute__((amdgpu_flat_work_group_size(NTHR, NTHR), amdgpu_waves_per_eu(4, 4)))
void lstm2_kernel(const float* __restrict__ input,
                  const float* __restrict__ W_ih1, const float* __restrict__ W_hh1,
                  const float* __restrict__ b_ih1, const float* __restrict__ b_hh1,
                  const float* __restrict__ W_ih2, const float* __restrict__ W_hh2,
                  const float* __restrict__ b_ih2, const float* __restrict__ b_hh2,
                  const float* __restrict__ W_lin, const float* __restrict__ b_lin,
                  float* __restrict__ out)
{
    const int tid  = threadIdx.x;
    const int w    = tid >> 6;        // wave 0..13
    const int lane = tid & 63;
    const int q    = lane >> 4;       // quad
    const int mcol = lane & 15;       // batch column (and A-frag m)
    const int b0   = blockIdx.x * BPB;

    const bool tile_wave = (w < 13);
    const bool y_wave    = (w == 13);

    // [buf][plane][mcol][kpos]; planes: 0=h1 1=h2 (fp16, k-permuted layout).
    // Positions of units>=51 stay zero (init below; unit 51 writes exact 0).
    __shared__ __align__(16) _Float16 hb[2][2][BPB][KPAD];

    {
        _Float16* hz = &hb[0][0][0][0];
        for (int i = tid; i < 2 * 2 * BPB * KPAD; i += NTHR) hz[i] = (_Float16)0.0f;
    }

    // ---- persistent weight fragments: wave w owns tile w ------------------
    half8 A1[2], Ai[2], Ah[2];            // W_hh1 / W_ih2 / W_hh2, x Ktile
    f4 bb1, bb2, wxv;
    float c1 = 0.0f, c2 = 0.0f;
    const int t = w;                      // tile
    const int u = 4 * t + q;              // this lane's unit (<= 51 for t<13)
    const int wpos = posu(u);             // permuted store position

    if (tile_wave) {
#pragma unroll
        for (int kt = 0; kt < 2; ++kt) {
            A1[kt] = load_wfrag(W_hh1, t, kt, q, mcol);
            Ai[kt] = load_wfrag(W_ih2, t, kt, q, mcol);
            Ah[kt] = load_wfrag(W_hh2, t, kt, q, mcol);
        }
#pragma unroll
        for (int j = 0; j < 4; ++j) {     // gate j of unit u (PyTorch row j*H+u)
            const bool v = (u < H);
            const float sc = (j == 2) ? LOG2E2 : LOG2E;
            bb1[j] = v ? sc * (b_ih1[j * H + u] + b_hh1[j * H + u]) : 0.0f;
            bb2[j] = v ? sc * (b_ih2[j * H + u] + b_hh2[j * H + u]) : 0.0f;
            wxv[j] = v ? sc * W_ih1[j * H + u] : 0.0f;
        }
    }

    float wl[16];                   // wave13: y weights for PERMUTED positions
    if (y_wave) {
#pragma unroll
        for (int i = 0; i < 16; ++i) {
            const int r = ipos(q * 16 + i);
            wl[i] = (r < H) ? W_lin[r] : 0.0f;
        }
    }
    const float blin = b_lin[0];

    float xcur = input[(size_t)(b0 + mcol) * TLEN + 0];

    __syncthreads();                       // zeros visible (full sync once)

// One LSTM step: reads buf RB (h1(k-1), h2(k-2)), writes buf WB.
// RB/WB/L2EN/YEN are literals -> guards fold, LDS addresses loop-invariant.
#define STEP(KK, RB, WB, L2EN, YEN)                                            \
do {                                                                           \
    const int k_  = (KK);                                                      \
    const int kn_ = (k_ + 1 < TLEN) ? (k_ + 1) : (TLEN - 1);                   \
    const float xnext_ = input[(size_t)(b0 + mcol) * TLEN + kn_];              \
    if (tile_wave) {                                                           \
        half8 B1a = lds8h(&hb[RB][0][mcol][q * 8]);                            \
        half8 B1b = lds8h(&hb[RB][0][mcol][32 + q * 8]);                       \
        f4 g1;                                                                 \
        g1[0] = fmaf(wxv[0], xcur, bb1[0]);                                    \
        g1[1] = fmaf(wxv[1], xcur, bb1[1]);                                    \
        g1[2] = fmaf(wxv[2], xcur, bb1[2]);                                    \
        g1[3] = fmaf(wxv[3], xcur, bb1[3]);                                    \
        MFMA(g1, A1[0], B1a);  MFMA(g1, A1[1], B1b);                           \
        /* L1 acts (step k) */                                                 \
        const float h1n = cell(g1[0], g1[1], g1[2], g1[3], &c1);               \
        hb[WB][0][mcol][wpos] = (_Float16)h1n;                                 \
        if (L2EN) {                                                            \
            half8 B2a = lds8h(&hb[RB][1][mcol][q * 8]);                        \
            half8 B2b = lds8h(&hb[RB][1][mcol][32 + q * 8]);                   \
            f4 g2 = bb2;                                                       \
            MFMA(g2, Ai[0], B1a);  MFMA(g2, Ai[1], B1b);                       \
            MFMA(g2, Ah[0], B2a);  MFMA(g2, Ah[1], B2b);                       \
            /* L2 acts (step k-1) */                                           \
            const float h2n = cell(g2[0], g2[1], g2[2], g2[3], &c2);           \
            hb[WB][1][mcol][wpos] = (_Float16)h2n;                             \
        }                                                                      \
    } else if (y_wave && (YEN)) {                                              \
        /* deferred y(k-2) from h2 plane of buf RB (stable this iter) */       \
        half8 y0 = lds8h(&hb[RB][1][mcol][q * 16]);                            \
        half8 y1 = lds8h(&hb[RB][1][mcol][q * 16 + 8]);                        \
        float yp = 0.0f;                                                       \
        _Pragma("unroll")                                                      \
        for (int i = 0; i < 8; ++i) {                                          \
            yp += wl[i]     * (float)y0[i];                                    \
            yp += wl[i + 8] * (float)y1[i];                                    \
        }                                                                      \
        yp += __shfl_xor(yp, 16);                                              \
        yp += __shfl_xor(yp, 32);                                              \
        if (q == 0) out[(size_t)(b0 + mcol) * TLEN + (k_ - 2)] = yp + blin;    \
    }                                                                          \
    block_sync_lds();                                                          \
    xcur = xnext_;                                                             \
} while (0)

    // k even: rb=1, wbuf=0; k odd: rb=0, wbuf=1.
    STEP(0, 1, 0, 0, 0);                   // L1 only (h2(-1) stays 0)
    STEP(1, 0, 1, 1, 0);                   // +L2 (step 0); y starts at k=2
    for (int k = 2; k < TLEN; k += 2) {    // steady: no guards
        STEP(k, 1, 0, 1, 1);
        STEP(k + 1, 0, 1, 1, 1);
    }
    STEP(TLEN, 1, 0, 1, 1);                // tail: L2(step 1023) + y(1022)
#undef STEP

    // epilogue: y(T-1) from h2 plane of buf (TLEN & 1) = 0 (= wbuf at k=TLEN)
    if (y_wave) {
        half8 y0 = lds8h(&hb[0][1][mcol][q * 16]);
        half8 y1 = lds8h(&hb[0][1][mcol][q * 16 + 8]);
        float yp = 0.0f;
#pragma unroll
        for (int i = 0; i < 8; ++i) {
            yp += wl[i]     * (float)y0[i];
            yp += wl[i + 8] * (float)y1[i];
        }
        yp += __shfl_xor(yp, 16);
        yp += __shfl_xor(yp, 32);
        if (q == 0) out[(size_t)(b0 + mcol) * TLEN + (TLEN - 1)] = yp + blin;
    }
}

extern "C" void kernel_launch(void* const* d_in, const int* in_sizes, int n_in,
                              void* d_out, int out_size, void* d_ws, size_t ws_size,
                              hipStream_t stream)
{
    const float* input = (const float*)d_in[0];
    const float* W_ih1 = (const float*)d_in[1];
    const float* W_hh1 = (const float*)d_in[2];
    const float* b_ih1 = (const float*)d_in[3];
    const float* b_hh1 = (const float*)d_in[4];
    const float* W_ih2 = (const float*)d_in[5];
    const float* W_hh2 = (const float*)d_in[6];
    const float* b_ih2 = (const float*)d_in[7];
    const float* b_hh2 = (const float*)d_in[8];
    const float* W_lin = (const float*)d_in[9];
    const float* b_lin = (const float*)d_in[10];

    float* out = (float*)d_out;

    hipLaunchKernelGGL(lstm2_kernel, dim3(NBLK), dim3(NTHR), 0, stream,
                       input, W_ih1, W_hh1, b_ih1, b_hh1,
                       W_ih2, W_hh2, b_ih2, b_hh2, W_lin, b_lin,
                       out);
}